// Round 3
// baseline (87342.413 us; speedup 1.0000x reference)
//
#include <hip/hip_runtime.h>
#include <hip/hip_bf16.h>
#include <cstdint>
#include <cstddef>

// Problem: S=4096, I=1024, H=1024. 4H=4096. ALL tensors fp32 (per reference).
// out (fp32): all_hidden (4096 x 2048) then final_h (2048), flat.

typedef __attribute__((ext_vector_type(8))) short short8;
typedef __attribute__((ext_vector_type(4))) short short4v;
typedef __attribute__((ext_vector_type(4))) float float4v;

__device__ __forceinline__ float bf2f(unsigned short u) {
    return __uint_as_float(((unsigned int)u) << 16);
}
__device__ __forceinline__ unsigned short f2bf(float f) {
    __hip_bfloat16 h = __float2bfloat16(f);  // RNE
    return *reinterpret_cast<unsigned short*>(&h);
}

// ---------------------------------------------------------------------------
// Kernel A: x_proj[d][t][j] = b[d][j] + sum_k inp[t][k] * W[d][j][1024+k]
// fp32 inputs -> bf16 LDS tiles -> mfma_f32_16x16x32_bf16 -> fp32 x_proj.
// 128x128 tile, BK=32, 4 waves.
// ---------------------------------------------------------------------------
__global__ __launch_bounds__(256)
void xproj_gemm(const float* __restrict__ inp,
                const float* __restrict__ fw,
                const float* __restrict__ fb,
                const float* __restrict__ bw,
                const float* __restrict__ bb,
                float* __restrict__ xp)
{
    const int d  = blockIdx.z;
    const float* W = d ? bw : fw;
    const float* B = d ? bb : fb;
    const int t0 = blockIdx.y * 128;
    const int n0 = blockIdx.x * 128;

    __shared__ __align__(16) short Ash[128 * 32];
    __shared__ __align__(16) short Bsh[128 * 32];

    const int tid  = threadIdx.x;
    const int lane = tid & 63;
    const int wave = tid >> 6;
    const int wm = (wave & 1) * 64;
    const int wn = (wave >> 1) * 64;
    const int quad = lane >> 4;   // 0..3
    const int l15  = lane & 15;

    float4v acc[4][4];
    float4v zero4 = {0.f, 0.f, 0.f, 0.f};
#pragma unroll
    for (int mi = 0; mi < 4; mi++)
#pragma unroll
        for (int ni = 0; ni < 4; ni++) acc[mi][ni] = zero4;

    for (int k0 = 0; k0 < 1024; k0 += 32) {
        // stage: 128x32 fp32 -> bf16. 1024 float4-chunks per tile, 256 thr.
#pragma unroll
        for (int s = 0; s < 4; s++) {
            int c   = tid + s * 256;       // 0..1023
            int row = c >> 3;              // 0..127
            int ko  = (c & 7) * 4;         // 0,4,...,28
            float4v va = *(const float4v*)&inp[(size_t)(t0 + row) * 1024 + k0 + ko];
            float4v vb = *(const float4v*)&W[(size_t)(n0 + row) * 2048 + 1024 + k0 + ko];
            short4v sa, sb;
#pragma unroll
            for (int e = 0; e < 4; e++) {
                sa[e] = (short)f2bf(va[e]);
                sb[e] = (short)f2bf(vb[e]);
            }
            *(short4v*)&Ash[row * 32 + ko] = sa;
            *(short4v*)&Bsh[row * 32 + ko] = sb;
        }
        __syncthreads();

        short8 af[4], bfr[4];
#pragma unroll
        for (int mi = 0; mi < 4; mi++)
            af[mi] = *(const short8*)&Ash[(wm + mi * 16 + l15) * 32 + quad * 8];
#pragma unroll
        for (int ni = 0; ni < 4; ni++)
            bfr[ni] = *(const short8*)&Bsh[(wn + ni * 16 + l15) * 32 + quad * 8];

#pragma unroll
        for (int mi = 0; mi < 4; mi++)
#pragma unroll
            for (int ni = 0; ni < 4; ni++)
                acc[mi][ni] = __builtin_amdgcn_mfma_f32_16x16x32_bf16(
                    af[mi], bfr[ni], acc[mi][ni], 0, 0, 0);
        __syncthreads();
    }

#pragma unroll
    for (int ni = 0; ni < 4; ni++) {
        int gc = n0 + wn + ni * 16 + l15;
        float bias = B[gc];
#pragma unroll
        for (int mi = 0; mi < 4; mi++) {
#pragma unroll
            for (int r = 0; r < 4; r++) {
                int gr = t0 + wm + mi * 16 + quad * 4 + r;   // C/D: row=quad*4+reg
                xp[((size_t)d * 4096 + gr) * 4096 + gc] = acc[mi][ni][r] + bias;
            }
        }
    }
}

// ---------------------------------------------------------------------------
// Kernel B: persistent bidirectional LSTM recurrence (fp32).
// FUSED=0: x_proj precomputed in ws. FUSED=1: Wx (packed bf16) in regs,
// inp row staged to LDS per step (no big scratch needed).
// 128 blocks, all co-resident (1/CU). dir = bid&1, slot = bid>>1;
// block owns units [slot*16,+16) = 64 z-rows; Wh held fp32 in VGPRs.
// ---------------------------------------------------------------------------
template <int FUSED>
__global__ __launch_bounds__(512, 2)
void lstm_rec(const float* __restrict__ fw,
              const float* __restrict__ bw,
              const float* __restrict__ fb,
              const float* __restrict__ bb,
              const float* __restrict__ inp,
              const float* __restrict__ xp,
              unsigned int* __restrict__ hbuf,   // [dir][parity][1024] fp32 bits
              int* __restrict__ flags,           // [dir][64]
              float* __restrict__ out)
{
    const int dir  = blockIdx.x & 1;
    const int slot = blockIdx.x >> 1;
    const int u0   = slot * 16;
    const int T    = threadIdx.x;      // 0..511
    const int rl   = T & 63;           // row-local 0..63
    const int gate = rl >> 4;
    const int ul   = rl & 15;
    const int chunk = T >> 6;          // wave id 0..7
    const int j    = gate * 1024 + u0 + ul;   // global z-row
    const float* W = dir ? bw : fw;

    __shared__ __align__(16) float hsh[1024];
    __shared__ __align__(16) float xsh[1024];
    __shared__ float psum[64 * 9];
    __shared__ float zsh[64];
    __shared__ float hnew[16];

    // Wh weights (cols [chunk*128,+128) of row j) -> fp32 regs, no conversion
    float w[128];
    {
        const float* wr = W + (size_t)j * 2048 + chunk * 128;
#pragma unroll
        for (int i = 0; i < 32; i++)
            *(float4v*)&w[4 * i] = *(const float4v*)&wr[4 * i];
    }

    // FUSED: Wx packed bf16 (64 dwords) + bias
    unsigned int w2[64];
    float bj = 0.f;
    if (FUSED) {
        const float* wr2 = W + (size_t)j * 2048 + 1024 + chunk * 128;
#pragma unroll
        for (int i = 0; i < 32; i++) {
            float4v v = *(const float4v*)&wr2[4 * i];
            w2[2 * i]     = (unsigned int)f2bf(v[0]) | ((unsigned int)f2bf(v[1]) << 16);
            w2[2 * i + 1] = (unsigned int)f2bf(v[2]) | ((unsigned int)f2bf(v[3]) << 16);
        }
        if (T < 64) bj = (dir ? bb : fb)[j];
    }

    float c = 0.f;   // cell state for unit u0+T (threads T<16)

    for (int t = 0; t < 4096; t++) {
        const int tr = dir ? (4095 - t) : t;

        float xv = 0.f;
        if (FUSED) {
            const float2* ir = (const float2*)&inp[(size_t)tr * 1024];
            float2 v = ir[T];
            xsh[2 * T]     = v.x;
            xsh[2 * T + 1] = v.y;
            xv = bj;
        } else if (T < 64) {
            xv = xp[((size_t)dir * 4096 + tr) * 4096 + j];
        }

        if (t == 0) {
            hsh[2 * T]     = 0.f;
            hsh[2 * T + 1] = 0.f;
        } else {
            if (T < 64) {
                while (__hip_atomic_load(&flags[dir * 64 + T], __ATOMIC_ACQUIRE,
                                         __HIP_MEMORY_SCOPE_AGENT) < t) { }
            }
            __syncthreads();
            unsigned int d0 = __hip_atomic_load(
                &hbuf[dir * 2048 + (t & 1) * 1024 + 2 * T],
                __ATOMIC_RELAXED, __HIP_MEMORY_SCOPE_AGENT);
            unsigned int d1 = __hip_atomic_load(
                &hbuf[dir * 2048 + (t & 1) * 1024 + 2 * T + 1],
                __ATOMIC_RELAXED, __HIP_MEMORY_SCOPE_AGENT);
            hsh[2 * T]     = __uint_as_float(d0);
            hsh[2 * T + 1] = __uint_as_float(d1);
        }
        __syncthreads();

        // z partial: 128 reg-resident fp32 MACs (+128 bf16 Wx MACs if FUSED)
        float a0 = 0.f, a1 = 0.f, a2 = 0.f, a3 = 0.f;
        const float4v* h4 = (const float4v*)&hsh[chunk * 128];
#pragma unroll
        for (int i = 0; i < 32; i++) {
            float4v hv = h4[i];
            a0 = __builtin_fmaf(w[4 * i + 0], hv.x, a0);
            a1 = __builtin_fmaf(w[4 * i + 1], hv.y, a1);
            a2 = __builtin_fmaf(w[4 * i + 2], hv.z, a2);
            a3 = __builtin_fmaf(w[4 * i + 3], hv.w, a3);
        }
        if (FUSED) {
            const float* xs = &xsh[chunk * 128];
#pragma unroll
            for (int i = 0; i < 64; i++) {
                unsigned int dv = w2[i];
                a0 = __builtin_fmaf(bf2f((unsigned short)(dv & 0xffffu)),
                                    xs[2 * i], a0);
                a1 = __builtin_fmaf(bf2f((unsigned short)(dv >> 16)),
                                    xs[2 * i + 1], a1);
            }
        }
        psum[rl * 9 + chunk] = (a0 + a1) + (a2 + a3);
        __syncthreads();

        if (T < 64) {
            float z = xv;
#pragma unroll
            for (int i = 0; i < 8; i++) z += psum[T * 9 + i];
            zsh[T] = z;
        }
        __syncthreads();

        if (T < 16) {
            float fz = zsh[T], iz = zsh[16 + T], gz = zsh[32 + T], oz = zsh[48 + T];
            float sf = 1.f / (1.f + __expf(-fz));
            float si = 1.f / (1.f + __expf(-iz));
            float so = 1.f / (1.f + __expf(-oz));
            c = sf * c + si * tanhf(gz);
            hnew[T] = so * tanhf(c);
        }
        __syncthreads();

        if (T < 16) {
            float hv = hnew[T];
            __hip_atomic_store(&hbuf[dir * 2048 + ((t + 1) & 1) * 1024 + u0 + T],
                               __float_as_uint(hv),
                               __ATOMIC_RELAXED, __HIP_MEMORY_SCOPE_AGENT);
            out[(size_t)tr * 2048 + dir * 1024 + u0 + T] = hv;
            if (t == 4095)   // final_h: fwd = hs[4095], bwd = hs[0]
                out[(size_t)4096 * 2048 + dir * 1024 + u0 + T] = hv;
        }
        __threadfence();
        __syncthreads();
        if (T == 0) {
            __hip_atomic_store(&flags[dir * 64 + slot], t + 1,
                               __ATOMIC_RELEASE, __HIP_MEMORY_SCOPE_AGENT);
        }
    }
}

// ---------------------------------------------------------------------------
extern "C" void kernel_launch(void* const* d_in, const int* in_sizes, int n_in,
                              void* d_out, int out_size, void* d_ws, size_t ws_size,
                              hipStream_t stream)
{
    const float* inp = (const float*)d_in[0];
    const float* fw  = (const float*)d_in[1];
    const float* fb  = (const float*)d_in[2];
    const float* bw  = (const float*)d_in[3];
    const float* bb  = (const float*)d_in[4];

    char* ws = (char*)d_ws;
    unsigned int* hbuf = (unsigned int*)ws;        // 16 KB: [dir][parity][1024]
    int* flags = (int*)(ws + 16384);               // 512 B
    float* xp  = (float*)(ws + 32768);             // x_proj: 2 x 4096 x 4096 fp32

    const size_t XP_BYTES = 2ull * 4096 * 4096 * 4;   // 134.2 MB
    const int have_xp = (ws_size >= 32768 + XP_BYTES);

    hipMemsetAsync(ws, 0, 32768, stream);   // zero hbuf + flags

    float* outp = (float*)d_out;
    if (have_xp) {
        dim3 gg(32, 32, 2);
        xproj_gemm<<<gg, 256, 0, stream>>>(inp, fw, fb, bw, bb, xp);
        lstm_rec<0><<<dim3(128), 512, 0, stream>>>(fw, bw, fb, bb, inp, xp,
                                                   hbuf, flags, outp);
    } else {
        lstm_rec<1><<<dim3(128), 512, 0, stream>>>(fw, bw, fb, bb, inp, nullptr,
                                                   hbuf, flags, outp);
    }
}

// Round 4
// 9593.119 us; speedup vs baseline: 9.1047x; 9.1047x over previous
//
#include <hip/hip_runtime.h>
#include <hip/hip_bf16.h>
#include <cstdint>
#include <cstddef>

// Problem: S=4096, I=1024, H=1024. 4H=4096. ALL tensors fp32 (per reference).
// out (fp32): all_hidden (4096 x 2048) then final_h (2048), flat.

typedef __attribute__((ext_vector_type(8))) short short8;
typedef __attribute__((ext_vector_type(4))) short short4v;
typedef __attribute__((ext_vector_type(4))) float float4v;
typedef unsigned long long ull;

__device__ __forceinline__ float bf2f(unsigned short u) {
    return __uint_as_float(((unsigned int)u) << 16);
}
__device__ __forceinline__ unsigned short f2bf(float f) {
    __hip_bfloat16 h = __float2bfloat16(f);  // RNE
    return *reinterpret_cast<unsigned short*>(&h);
}
__device__ __forceinline__ float sigm(float x) {
    return 1.f / (1.f + __expf(-x));
}
__device__ __forceinline__ float tanh_fast(float x) {
    return 1.f - 2.f / (__expf(2.f * x) + 1.f);   // exact at +-inf, ~1e-6 rel
}

// ---------------------------------------------------------------------------
// Kernel A: x_proj[d][t][j] = b[d][j] + sum_k inp[t][k] * W[d][j][1024+k]
// fp32 -> bf16 LDS tiles -> mfma_f32_16x16x32_bf16 -> fp32 x_proj.
// ---------------------------------------------------------------------------
__global__ __launch_bounds__(256)
void xproj_gemm(const float* __restrict__ inp,
                const float* __restrict__ fw,
                const float* __restrict__ fb,
                const float* __restrict__ bw,
                const float* __restrict__ bb,
                float* __restrict__ xp)
{
    const int d  = blockIdx.z;
    const float* W = d ? bw : fw;
    const float* B = d ? bb : fb;
    const int t0 = blockIdx.y * 128;
    const int n0 = blockIdx.x * 128;

    __shared__ __align__(16) short Ash[128 * 32];
    __shared__ __align__(16) short Bsh[128 * 32];

    const int tid  = threadIdx.x;
    const int lane = tid & 63;
    const int wave = tid >> 6;
    const int wm = (wave & 1) * 64;
    const int wn = (wave >> 1) * 64;
    const int quad = lane >> 4;
    const int l15  = lane & 15;

    float4v acc[4][4];
    float4v zero4 = {0.f, 0.f, 0.f, 0.f};
#pragma unroll
    for (int mi = 0; mi < 4; mi++)
#pragma unroll
        for (int ni = 0; ni < 4; ni++) acc[mi][ni] = zero4;

    for (int k0 = 0; k0 < 1024; k0 += 32) {
#pragma unroll
        for (int s = 0; s < 4; s++) {
            int c   = tid + s * 256;       // 0..1023
            int row = c >> 3;              // 0..127
            int ko  = (c & 7) * 4;         // 0..28
            float4v va = *(const float4v*)&inp[(size_t)(t0 + row) * 1024 + k0 + ko];
            float4v vb = *(const float4v*)&W[(size_t)(n0 + row) * 2048 + 1024 + k0 + ko];
            short4v sa, sb;
#pragma unroll
            for (int e = 0; e < 4; e++) {
                sa[e] = (short)f2bf(va[e]);
                sb[e] = (short)f2bf(vb[e]);
            }
            *(short4v*)&Ash[row * 32 + ko] = sa;
            *(short4v*)&Bsh[row * 32 + ko] = sb;
        }
        __syncthreads();

        short8 af[4], bfr[4];
#pragma unroll
        for (int mi = 0; mi < 4; mi++)
            af[mi] = *(const short8*)&Ash[(wm + mi * 16 + l15) * 32 + quad * 8];
#pragma unroll
        for (int ni = 0; ni < 4; ni++)
            bfr[ni] = *(const short8*)&Bsh[(wn + ni * 16 + l15) * 32 + quad * 8];

#pragma unroll
        for (int mi = 0; mi < 4; mi++)
#pragma unroll
            for (int ni = 0; ni < 4; ni++)
                acc[mi][ni] = __builtin_amdgcn_mfma_f32_16x16x32_bf16(
                    af[mi], bfr[ni], acc[mi][ni], 0, 0, 0);
        __syncthreads();
    }

#pragma unroll
    for (int ni = 0; ni < 4; ni++) {
        int gc = n0 + wn + ni * 16 + l15;
        float bias = B[gc];
#pragma unroll
        for (int mi = 0; mi < 4; mi++) {
#pragma unroll
            for (int r = 0; r < 4; r++) {
                int gr = t0 + wm + mi * 16 + quad * 4 + r;
                xp[((size_t)d * 4096 + gr) * 4096 + gc] = acc[mi][ni][r] + bias;
            }
        }
    }
}

// ---------------------------------------------------------------------------
// Kernel B: persistent bidirectional LSTM recurrence, fence-free tagged sync.
// hq[dir][parity][unit] : 64-bit word = (step_tag << 32) | f32bits(h).
// All cross-block traffic is RELAXED agent-scope atomics (sc1, bypasses the
// non-coherent per-XCD L2; NO buffer_inv / buffer_wbl2 cache storms).
// Tag==t proves payload is h^t (data+tag in one single-copy-atomic word).
// Double-buffer by parity; producer can only publish t+1 after all its own
// tag-t polls succeeded -> no word is clobbered while still needed.
// 128 blocks (1/CU, co-resident). dir=bid&1, slot=bid>>1, 16 units/block.
// ---------------------------------------------------------------------------
template <int FUSED>
__global__ __launch_bounds__(512, 2)
void lstm_rec(const float* __restrict__ fw,
              const float* __restrict__ bw,
              const float* __restrict__ fb,
              const float* __restrict__ bb,
              const float* __restrict__ inp,
              const float* __restrict__ xp,
              ull* __restrict__ hq,              // [dir][2][1024] tagged words
              float* __restrict__ out)
{
    const int dir  = blockIdx.x & 1;
    const int slot = blockIdx.x >> 1;
    const int u0   = slot * 16;
    const int T    = threadIdx.x;      // 0..511
    const int rl   = T & 63;           // z-row-local 0..63
    const int gate = rl >> 4;
    const int ul   = rl & 15;
    const int chunk = T >> 6;          // wave id 0..7
    const int j    = gate * 1024 + u0 + ul;   // global z-row
    const float* W = dir ? bw : fw;

    __shared__ __align__(16) float hsh[1024];
    __shared__ __align__(16) float xsh[1024];     // FUSED only
    __shared__ float xvs[2][64];                  // per-parity xp values
    __shared__ float psum[2][64 * 9];             // per-parity partials

    // Wh weights (cols [chunk*128,+128) of row j) -> fp32 regs
    float w[128];
    {
        const float* wr = W + (size_t)j * 2048 + chunk * 128;
#pragma unroll
        for (int i = 0; i < 32; i++)
            *(float4v*)&w[4 * i] = *(const float4v*)&wr[4 * i];
    }

    // FUSED: Wx packed bf16 + per-thread bias for the 4 owned z-rows
    unsigned int w2[64];
    float bj4[4];
    if (FUSED) {
        const float* wr2 = W + (size_t)j * 2048 + 1024 + chunk * 128;
#pragma unroll
        for (int i = 0; i < 32; i++) {
            float4v v = *(const float4v*)&wr2[4 * i];
            w2[2 * i]     = (unsigned int)f2bf(v[0]) | ((unsigned int)f2bf(v[1]) << 16);
            w2[2 * i + 1] = (unsigned int)f2bf(v[2]) | ((unsigned int)f2bf(v[3]) << 16);
        }
        if (T < 16) {
#pragma unroll
            for (int g = 0; g < 4; g++)
                bj4[g] = (dir ? bb : fb)[g * 1024 + u0 + T];
        }
    }

    ull* hqd = hq + dir * 2048;
    float c = 0.f;   // cell state for unit u0+T (threads T<16)

    for (int t = 0; t < 4096; t++) {
        const int tr  = dir ? (4095 - t) : t;
        const int par = t & 1;

        // independent global loads first (long latency, off critical path)
        float xv = 0.f;
        float2 iv;
        if (FUSED) {
            iv = ((const float2*)&inp[(size_t)tr * 1024])[T];
        } else if (T < 64) {
            xv = xp[((size_t)dir * 4096 + tr) * 4096 + j];
        }

        // poll my two units' tagged words (relaxed, no cache maintenance)
        {
            ull* q0 = &hqd[par * 1024 + 2 * T];
            ull w0 = __hip_atomic_load(q0, __ATOMIC_RELAXED, __HIP_MEMORY_SCOPE_AGENT);
            ull w1 = __hip_atomic_load(q0 + 1, __ATOMIC_RELAXED, __HIP_MEMORY_SCOPE_AGENT);
            while ((unsigned)(w0 >> 32) != (unsigned)t)
                w0 = __hip_atomic_load(q0, __ATOMIC_RELAXED, __HIP_MEMORY_SCOPE_AGENT);
            while ((unsigned)(w1 >> 32) != (unsigned)t)
                w1 = __hip_atomic_load(q0 + 1, __ATOMIC_RELAXED, __HIP_MEMORY_SCOPE_AGENT);
            hsh[2 * T]     = __uint_as_float((unsigned)w0);
            hsh[2 * T + 1] = __uint_as_float((unsigned)w1);
        }
        if (FUSED) {
            xsh[2 * T]     = iv.x;
            xsh[2 * T + 1] = iv.y;
        } else if (T < 64) {
            xvs[par][T] = xv;
        }
        __syncthreads();   // S1: hsh (+xsh/xvs) ready

        // z partial: 128 reg-resident fp32 MACs (broadcast LDS h reads)
        float a0 = 0.f, a1 = 0.f, a2 = 0.f, a3 = 0.f;
        const float4v* h4 = (const float4v*)&hsh[chunk * 128];
#pragma unroll
        for (int i = 0; i < 32; i++) {
            float4v hv = h4[i];
            a0 = __builtin_fmaf(w[4 * i + 0], hv.x, a0);
            a1 = __builtin_fmaf(w[4 * i + 1], hv.y, a1);
            a2 = __builtin_fmaf(w[4 * i + 2], hv.z, a2);
            a3 = __builtin_fmaf(w[4 * i + 3], hv.w, a3);
        }
        if (FUSED) {
            const float* xs = &xsh[chunk * 128];
#pragma unroll
            for (int i = 0; i < 64; i++) {
                unsigned int dv = w2[i];
                a0 = __builtin_fmaf(bf2f((unsigned short)(dv & 0xffffu)),
                                    xs[2 * i], a0);
                a1 = __builtin_fmaf(bf2f((unsigned short)(dv >> 16)),
                                    xs[2 * i + 1], a1);
            }
        }
        psum[par][rl * 9 + chunk] = (a0 + a1) + (a2 + a3);
        __syncthreads();   // S2: psum ready

        // epilogue on 16 threads: gates for unit u0+T, publish tagged word.
        // No trailing barrier: psum/xvs are parity-indexed; next S1 cannot
        // pass until these threads arrive there.
        if (T < 16) {
            float z[4];
#pragma unroll
            for (int g = 0; g < 4; g++) {
                int row = g * 16 + T;
                float s = FUSED ? bj4[g] : xvs[par][row];
                const float* pp = &psum[par][row * 9];
#pragma unroll
                for (int cc = 0; cc < 8; cc++) s += pp[cc];
                z[g] = s;
            }
            c = sigm(z[0]) * c + sigm(z[1]) * tanh_fast(z[2]);
            float hv = sigm(z[3]) * tanh_fast(c);
            out[(size_t)tr * 2048 + dir * 1024 + u0 + T] = hv;
            if (t == 4095)   // final_h: fwd = hs[4095], bwd = hs[0]
                out[(size_t)4096 * 2048 + dir * 1024 + u0 + T] = hv;
            __hip_atomic_store(&hqd[((t + 1) & 1) * 1024 + u0 + T],
                               ((ull)(unsigned)(t + 1) << 32) | __float_as_uint(hv),
                               __ATOMIC_RELAXED, __HIP_MEMORY_SCOPE_AGENT);
        }
    }
}

// ---------------------------------------------------------------------------
extern "C" void kernel_launch(void* const* d_in, const int* in_sizes, int n_in,
                              void* d_out, int out_size, void* d_ws, size_t ws_size,
                              hipStream_t stream)
{
    const float* inp = (const float*)d_in[0];
    const float* fw  = (const float*)d_in[1];
    const float* fb  = (const float*)d_in[2];
    const float* bw  = (const float*)d_in[3];
    const float* bb  = (const float*)d_in[4];

    char* ws = (char*)d_ws;
    ull* hq   = (ull*)ws;                          // 32 KB: [dir][2][1024] x 8B
    float* xp = (float*)(ws + 32768);              // x_proj: 2 x 4096 x 4096 fp32

    const size_t XP_BYTES = 2ull * 4096 * 4096 * 4;   // 134.2 MB
    const int have_xp = (ws_size >= 32768 + XP_BYTES);

    hipMemsetAsync(ws, 0, 32768, stream);   // tag 0 / h=0 == step-0 state

    float* outp = (float*)d_out;
    if (have_xp) {
        dim3 gg(32, 32, 2);
        xproj_gemm<<<gg, 256, 0, stream>>>(inp, fw, fb, bw, bb, xp);
        lstm_rec<0><<<dim3(128), 512, 0, stream>>>(fw, bw, fb, bb, inp, xp,
                                                   hq, outp);
    } else {
        lstm_rec<1><<<dim3(128), 512, 0, stream>>>(fw, bw, fb, bb, inp, nullptr,
                                                   hq, outp);
    }
}